// Round 1
// baseline (2191.731 us; speedup 1.0000x reference)
//
#include <hip/hip_runtime.h>
#include <hip/hip_bf16.h>

// RGAT encoder: R=3 relations, N=100000 nodes, E=500000 edges/rel, H=4, F=64, IN=256.
// Round 1: correctness-first f32 pipeline.
//   per r: z = x@W_r (tiled f32 GEMM) -> el/er (block/node reduce) ->
//          edge exp+den (atomicAdd) -> weighted scatter (atomicAdd into d_out)
//   finalize: ELU(acc + sum_r bias_r) in-place.
// Softmax max-subtraction skipped: alpha = exp(e)/sum(exp(e)) is mathematically
// identical; |e| <= ~7 for this data so fp32 exp is safe.

#define RGAT_N 100000
#define RGAT_E 500000
#define RGAT_H 4
#define RGAT_F 64
#define RGAT_IN 256
#define RGAT_R 3
#define RGAT_HF 256

// ---------------- GEMM: C[M,256] = A[M,256] @ B[256,256] (f32) ----------------
#define BM 64
#define BN 64
#define BK 16

__global__ __launch_bounds__(256) void rgat_gemm_f32(
    const float* __restrict__ A, const float* __restrict__ B,
    float* __restrict__ C, int M) {
  __shared__ float As[BK][BM + 1];
  __shared__ float Bs[BK][BN + 4];

  const int tid = threadIdx.x;
  const int tx = tid & 15;
  const int ty = tid >> 4;
  const int m0 = blockIdx.x * BM;
  const int n0 = blockIdx.y * BN;

  float acc[4][4] = {};

  for (int k0 = 0; k0 < RGAT_IN; k0 += BK) {
    // Load A tile: rows m0..m0+63, cols k0..k0+15; 4 consecutive floats/thread.
    {
      const int idx = tid * 4;        // 0..1023
      const int row = idx >> 4;       // 0..63
      const int col = idx & 15;       // 0,4,8,12
      const int m = m0 + row;
      float4 v = make_float4(0.f, 0.f, 0.f, 0.f);
      if (m < M) v = *(const float4*)(A + (size_t)m * RGAT_IN + k0 + col);
      As[col + 0][row] = v.x;
      As[col + 1][row] = v.y;
      As[col + 2][row] = v.z;
      As[col + 3][row] = v.w;
    }
    // Load B tile: rows k0..k0+15, cols n0..n0+63.
    {
      const int idx = tid * 4;        // 0..1023
      const int row = idx >> 6;       // 0..15
      const int col = idx & 63;       // multiple of 4
      const float4 v = *(const float4*)(B + (size_t)(k0 + row) * RGAT_HF + n0 + col);
      *(float4*)&Bs[row][col] = v;
    }
    __syncthreads();

#pragma unroll
    for (int kk = 0; kk < BK; ++kk) {
      float a[4];
#pragma unroll
      for (int i = 0; i < 4; ++i) a[i] = As[kk][ty * 4 + i];
      const float4 bv = *(const float4*)&Bs[kk][tx * 4];
      const float b4[4] = {bv.x, bv.y, bv.z, bv.w};
#pragma unroll
      for (int i = 0; i < 4; ++i)
#pragma unroll
        for (int j = 0; j < 4; ++j) acc[i][j] += a[i] * b4[j];
    }
    __syncthreads();
  }

#pragma unroll
  for (int i = 0; i < 4; ++i) {
    const int m = m0 + ty * 4 + i;
    if (m < M) {
      float4 v = make_float4(acc[i][0], acc[i][1], acc[i][2], acc[i][3]);
      *(float4*)(C + (size_t)m * RGAT_HF + n0 + tx * 4) = v;
    }
  }
}

// ---------------- per-node attention logits ----------------
__global__ __launch_bounds__(256) void rgat_attn_logits(
    const float* __restrict__ z, const float* __restrict__ al,
    const float* __restrict__ ar, float* __restrict__ el,
    float* __restrict__ er) {
  const int n = blockIdx.x;
  const int t = threadIdx.x;
  const float zv = z[(size_t)n * RGAT_HF + t];
  float l = zv * al[t];
  float rr = zv * ar[t];
#pragma unroll
  for (int off = 32; off; off >>= 1) {
    l += __shfl_down(l, off);
    rr += __shfl_down(rr, off);
  }
  const int h = t >> 6;
  const int f = t & 63;
  if (f == 0) {
    el[n * RGAT_H + h] = l;
    er[n * RGAT_H + h] = rr;
  }
}

// ---------------- edge pass 1: ee = exp(leakyrelu(el[s]+er[d])), den += ee ----
__global__ __launch_bounds__(256) void rgat_edge_exp(
    const float* __restrict__ el, const float* __restrict__ er,
    const int* __restrict__ src, const int* __restrict__ dst,
    float* __restrict__ ee, float* __restrict__ den) {
  const int i = blockIdx.x * 256 + threadIdx.x;
  if (i >= RGAT_E * RGAT_H) return;
  const int e = i >> 2;
  const int h = i & 3;
  const int s = src[e];
  const int d = dst[e];
  float v = el[s * RGAT_H + h] + er[d * RGAT_H + h];
  v = v > 0.f ? v : 0.2f * v;
  const float p = __expf(v);
  ee[i] = p;
  atomicAdd(&den[d * RGAT_H + h], p);
}

// ---------------- edge pass 2: acc[dst] += z[src] * alpha ----------------
__global__ __launch_bounds__(256) void rgat_edge_aggr(
    const float* __restrict__ z, const float* __restrict__ ee,
    const float* __restrict__ den, const int* __restrict__ src,
    const int* __restrict__ dst, float* __restrict__ acc) {
  const int w = (blockIdx.x * 256 + threadIdx.x) >> 6;
  const int lane = threadIdx.x & 63;
  if (w >= RGAT_E) return;
  const int s = src[w];
  const int d = dst[w];
  float alpha[RGAT_H];
#pragma unroll
  for (int j = 0; j < RGAT_H; ++j)
    alpha[j] = ee[w * RGAT_H + j] / den[d * RGAT_H + j];
  const size_t zs = (size_t)s * RGAT_HF;
  const size_t as = (size_t)d * RGAT_HF;
#pragma unroll
  for (int j = 0; j < RGAT_H; ++j) {
    const int c = j * 64 + lane;
    atomicAdd(&acc[as + c], z[zs + c] * alpha[j]);
  }
}

// ---------------- finalize: ELU(acc + bias_sum) ----------------
__global__ __launch_bounds__(256) void rgat_finalize(
    float* __restrict__ out, const float* __restrict__ bias) {
  const size_t i = (size_t)blockIdx.x * 256 + threadIdx.x;
  if (i >= (size_t)RGAT_N * RGAT_HF) return;
  const int c = (int)(i & 255);
  float v = out[i] + bias[c] + bias[RGAT_HF + c] + bias[2 * RGAT_HF + c];
  out[i] = v > 0.f ? v : (__expf(v) - 1.f);
}

extern "C" void kernel_launch(void* const* d_in, const int* in_sizes, int n_in,
                              void* d_out, int out_size, void* d_ws, size_t ws_size,
                              hipStream_t stream) {
  const float* x    = (const float*)d_in[0];
  const float* W    = (const float*)d_in[1];
  const float* al   = (const float*)d_in[2];
  const float* ar   = (const float*)d_in[3];
  const float* bias = (const float*)d_in[4];
  const int*   src  = (const int*)d_in[5];
  const int*   dst  = (const int*)d_in[6];
  float* out = (float*)d_out;

  // workspace layout (floats): z[N*256] | ee[E*4] | el[N*4] | er[N*4] | den[N*4]
  float* ws  = (float*)d_ws;
  float* z     = ws;
  float* eebuf = z + (size_t)RGAT_N * RGAT_HF;
  float* el    = eebuf + (size_t)RGAT_E * RGAT_H;
  float* er    = el + (size_t)RGAT_N * RGAT_H;
  float* den   = er + (size_t)RGAT_N * RGAT_H;

  hipMemsetAsync(d_out, 0, (size_t)RGAT_N * RGAT_HF * sizeof(float), stream);

  const dim3 ggrid((RGAT_N + BM - 1) / BM, RGAT_HF / BN);
  for (int r = 0; r < RGAT_R; ++r) {
    rgat_gemm_f32<<<ggrid, 256, 0, stream>>>(
        x, W + (size_t)r * RGAT_IN * RGAT_HF, z, RGAT_N);
    rgat_attn_logits<<<RGAT_N, 256, 0, stream>>>(
        z, al + (size_t)r * RGAT_HF, ar + (size_t)r * RGAT_HF, el, er);
    hipMemsetAsync(den, 0, (size_t)RGAT_N * RGAT_H * sizeof(float), stream);
    rgat_edge_exp<<<(RGAT_E * RGAT_H + 255) / 256, 256, 0, stream>>>(
        el, er, src + (size_t)r * RGAT_E, dst + (size_t)r * RGAT_E, eebuf, den);
    rgat_edge_aggr<<<(RGAT_E + 3) / 4, 256, 0, stream>>>(
        z, eebuf, den, src + (size_t)r * RGAT_E, dst + (size_t)r * RGAT_E, out);
  }
  rgat_finalize<<<((size_t)RGAT_N * RGAT_HF + 255) / 256, 256, 0, stream>>>(out, bias);
}

// Round 2
// 932.903 us; speedup vs baseline: 2.3494x; 2.3494x over previous
//
#include <hip/hip_runtime.h>
#include <hip/hip_bf16.h>

// RGAT encoder, round 2:
//  - bf16 MFMA GEMM (m97-style 128x128 tile, global_load_lds w=16, B^T input)
//  - device-built CSR (hist -> scan -> scatter), pull-based aggregation:
//    one wave per dst node, all 3 relations accumulated in registers,
//    single write of out with bias+ELU fused. No atomics on the z path.

#define RN 100000
#define RE 500000
#define RH 4
#define RF 64
#define RIN 256
#define RR 3
#define RHF 256
#define NE3 (RR * RE)      // 1,500,000 flat edges
#define N3  (RR * RN)      // 300,000 flat (rel,node)

typedef __attribute__((ext_vector_type(8))) short short8;
typedef __attribute__((ext_vector_type(4))) float f32x4;

static __device__ __forceinline__ float b2f(unsigned short u) {
  return __uint_as_float(((unsigned int)u) << 16);
}
static __device__ __forceinline__ unsigned short f2b(float f) {
  unsigned int u = __float_as_uint(f);
  u += 0x7FFF + ((u >> 16) & 1);   // RNE
  return (unsigned short)(u >> 16);
}

// ---------------- conversions ----------------
__global__ __launch_bounds__(256) void rgat_convx(
    const float* __restrict__ x, unsigned short* __restrict__ xb) {
  const size_t i = ((size_t)blockIdx.x * 256 + threadIdx.x) * 4;
  if (i >= (size_t)RN * RIN) return;
  const float4 v = *(const float4*)(x + i);
  ushort4 o;
  o.x = f2b(v.x); o.y = f2b(v.y); o.z = f2b(v.z); o.w = f2b(v.w);
  *(ushort4*)(xb + i) = o;
}

// W[r][k][n] f32 -> Wbt[r][n][k] bf16
__global__ __launch_bounds__(256) void rgat_convw(
    const float* __restrict__ W, unsigned short* __restrict__ wbt) {
  const int o = blockIdx.x * 256 + threadIdx.x;
  if (o >= RR * RIN * RHF) return;
  const int r = o / (RIN * RHF);
  const int rem = o - r * (RIN * RHF);
  const int n = rem >> 8;          // RIN = 256
  const int k = rem & 255;
  wbt[o] = f2b(W[r * (RIN * RHF) + k * RHF + n]);
}

// ---------------- GEMM: zb[r] = xb @ Wbt[r]^T, bf16 in/out, f32 acc ----------
__global__ __launch_bounds__(256) void rgat_gemm_bf16(
    const unsigned short* __restrict__ xb, const unsigned short* __restrict__ wbt,
    unsigned short* __restrict__ zb) {
  __shared__ unsigned short As[128 * 32];
  __shared__ unsigned short Bs[128 * 32];
  const int tid = threadIdx.x;
  const int lane = tid & 63, wid = tid >> 6;
  const int wr = wid >> 1, wc = wid & 1;
  const int m0 = blockIdx.x * 128;
  const int n0 = blockIdx.y * 128;
  const int r  = blockIdx.z;

  f32x4 acc[4][4] = {};

  const unsigned short* Bbase = wbt + (size_t)r * (RIN * RHF);

  for (int k0 = 0; k0 < RIN; k0 += 32) {
#pragma unroll
    for (int i = 0; i < 2; ++i) {
      const int c = wid * 128 + i * 64 + lane;   // 16B chunk id, 0..511
      const int row = c >> 2, c4 = c & 3;
      const unsigned short* ga = xb + (size_t)(m0 + row) * RIN + k0 + c4 * 8;
      __builtin_amdgcn_global_load_lds(
          (const __attribute__((address_space(1))) void*)ga,
          (__attribute__((address_space(3))) void*)(As + (wid * 128 + i * 64) * 8),
          16, 0, 0);
      const unsigned short* gb = Bbase + (size_t)(n0 + row) * RIN + k0 + c4 * 8;
      __builtin_amdgcn_global_load_lds(
          (const __attribute__((address_space(1))) void*)gb,
          (__attribute__((address_space(3))) void*)(Bs + (wid * 128 + i * 64) * 8),
          16, 0, 0);
    }
    asm volatile("s_waitcnt vmcnt(0)" ::: "memory");
    __syncthreads();

    short8 af[4], bfr[4];
#pragma unroll
    for (int mi = 0; mi < 4; ++mi)
      af[mi] = *(const short8*)(As + ((wr * 64 + mi * 16 + (lane & 15)) * 32 + (lane >> 4) * 8));
#pragma unroll
    for (int ni = 0; ni < 4; ++ni)
      bfr[ni] = *(const short8*)(Bs + ((wc * 64 + ni * 16 + (lane & 15)) * 32 + (lane >> 4) * 8));
#pragma unroll
    for (int mi = 0; mi < 4; ++mi)
#pragma unroll
      for (int ni = 0; ni < 4; ++ni)
        acc[mi][ni] = __builtin_amdgcn_mfma_f32_16x16x32_bf16(af[mi], bfr[ni], acc[mi][ni], 0, 0, 0);
    __syncthreads();
  }

  const int mbase = m0 + wr * 64;
#pragma unroll
  for (int mi = 0; mi < 4; ++mi) {
#pragma unroll
    for (int q = 0; q < 4; ++q) {
      const int m = mbase + mi * 16 + (lane >> 4) * 4 + q;
      if (m < RN) {
        unsigned short* zrow = zb + (size_t)r * ((size_t)RN * RHF) + (size_t)m * RHF
                               + n0 + wc * 64 + (lane & 15);
#pragma unroll
        for (int ni = 0; ni < 4; ++ni) zrow[ni * 16] = f2b(acc[mi][ni][q]);
      }
    }
  }
}

// ---------------- per-node attention logits (one wave per node, loops r) -----
__global__ __launch_bounds__(256) void rgat_logits(
    const unsigned short* __restrict__ zb, const float* __restrict__ al,
    const float* __restrict__ ar, float* __restrict__ el, float* __restrict__ er) {
  const int wid = threadIdx.x >> 6, lane = threadIdx.x & 63;
  const int n = blockIdx.x * 4 + wid;
  if (n >= RN) return;
  const int h = lane >> 4;
  const int c = lane * 4;
  for (int r = 0; r < RR; ++r) {
    const ushort4 zv = *(const ushort4*)(zb + (size_t)(r * (size_t)RN + n) * RHF + c);
    const float z0 = b2f(zv.x), z1 = b2f(zv.y), z2 = b2f(zv.z), z3 = b2f(zv.w);
    const float* alr = al + r * RHF;
    const float* arr = ar + r * RHF;
    float sl = z0 * alr[c] + z1 * alr[c + 1] + z2 * alr[c + 2] + z3 * alr[c + 3];
    float sr = z0 * arr[c] + z1 * arr[c + 1] + z2 * arr[c + 2] + z3 * arr[c + 3];
#pragma unroll
    for (int off = 1; off < 16; off <<= 1) {
      sl += __shfl_xor(sl, off);
      sr += __shfl_xor(sr, off);
    }
    if ((lane & 15) == 0) {
      el[(size_t)(r * (size_t)RN + n) * RH + h] = sl;
      er[(size_t)(r * (size_t)RN + n) * RH + h] = sr;
    }
  }
}

// ---------------- CSR build ----------------
__global__ __launch_bounds__(256) void rgat_hist(
    const int* __restrict__ dst, int* __restrict__ deg) {
  const int i = blockIdx.x * 256 + threadIdx.x;
  if (i >= NE3) return;
  const int r = i / RE;
  atomicAdd(&deg[r * RN + dst[i]], 1);
}

__global__ __launch_bounds__(256) void rgat_scan1(
    const int* __restrict__ deg, int* __restrict__ offs, int* __restrict__ bsum) {
  __shared__ int sh[256];
  const int tid = threadIdx.x;
  const int base = blockIdx.x * 1024 + tid * 4;
  int v[4]; int s = 0;
#pragma unroll
  for (int j = 0; j < 4; ++j) {
    v[j] = (base + j < N3) ? deg[base + j] : 0;
    s += v[j];
  }
  sh[tid] = s;
  __syncthreads();
  for (int off = 1; off < 256; off <<= 1) {
    int t = (tid >= off) ? sh[tid - off] : 0;
    __syncthreads();
    sh[tid] += t;
    __syncthreads();
  }
  int run = sh[tid] - s;   // exclusive prefix of this thread
  if (tid == 255) bsum[blockIdx.x] = sh[255];
#pragma unroll
  for (int j = 0; j < 4; ++j) {
    if (base + j < N3) offs[base + j] = run;
    run += v[j];
  }
}

__global__ __launch_bounds__(512) void rgat_scan2(int* __restrict__ bsum, int nb) {
  __shared__ int sh[512];
  const int tid = threadIdx.x;
  const int v = (tid < nb) ? bsum[tid] : 0;
  sh[tid] = v;
  __syncthreads();
  for (int off = 1; off < 512; off <<= 1) {
    int t = (tid >= off) ? sh[tid - off] : 0;
    __syncthreads();
    sh[tid] += t;
    __syncthreads();
  }
  if (tid < nb) bsum[tid] = sh[tid] - v;   // exclusive
}

__global__ __launch_bounds__(256) void rgat_scan3(
    int* __restrict__ offs, const int* __restrict__ bsum) {
  const int base = blockIdx.x * 1024 + threadIdx.x * 4;
  const int b = bsum[blockIdx.x];
#pragma unroll
  for (int j = 0; j < 4; ++j)
    if (base + j < N3) offs[base + j] += b;
}

// scatter: offs acts as cursor; afterwards offs[b] == segment END offset.
__global__ __launch_bounds__(256) void rgat_scatter(
    const int* __restrict__ dst, int* __restrict__ offs, int* __restrict__ eidx) {
  const int i = blockIdx.x * 256 + threadIdx.x;
  if (i >= NE3) return;
  const int r = i / RE;
  const int pos = atomicAdd(&offs[r * RN + dst[i]], 1);
  eidx[pos] = i;   // flat edge id (includes r*RE)
}

// ---------------- pull aggregation: one wave per dst node ----------------
__global__ __launch_bounds__(256) void rgat_aggregate(
    const unsigned short* __restrict__ zb, const float* __restrict__ el,
    const float* __restrict__ er, const int* __restrict__ src,
    const int* __restrict__ deg, const int* __restrict__ offs,
    const int* __restrict__ eidx, const float* __restrict__ bias,
    float* __restrict__ out) {
  const int wid = threadIdx.x >> 6, lane = threadIdx.x & 63;
  const int n = blockIdx.x * 4 + wid;
  if (n >= RN) return;
  const int h = lane >> 4;
  const int c = lane * 4;

  float acc0 = 0.f, acc1 = 0.f, acc2 = 0.f, acc3 = 0.f;

  for (int r = 0; r < RR; ++r) {
    const int base = r * RN + n;
    const int d = deg[base];
    if (d == 0) continue;
    const int start = offs[base] - d;
    const float erv = er[(size_t)base * RH + h];
    // pass 1: denominator for my head
    float den = 0.f;
    for (int e = 0; e < d; ++e) {
      const int j = eidx[start + e];
      const int s = src[j];
      float sc = el[(size_t)(r * (size_t)RN + s) * RH + h] + erv;
      sc = sc > 0.f ? sc : 0.2f * sc;
      den += __expf(sc);
    }
    const float inv = 1.f / den;
    // pass 2: weighted gather
    for (int e = 0; e < d; ++e) {
      const int j = eidx[start + e];
      const int s = src[j];
      float sc = el[(size_t)(r * (size_t)RN + s) * RH + h] + erv;
      sc = sc > 0.f ? sc : 0.2f * sc;
      const float a = __expf(sc) * inv;
      const ushort4 zv = *(const ushort4*)(zb + ((size_t)r * RN + s) * RHF + c);
      acc0 += a * b2f(zv.x);
      acc1 += a * b2f(zv.y);
      acc2 += a * b2f(zv.z);
      acc3 += a * b2f(zv.w);
    }
  }

  float v0 = acc0 + bias[c]     + bias[RHF + c]     + bias[2 * RHF + c];
  float v1 = acc1 + bias[c + 1] + bias[RHF + c + 1] + bias[2 * RHF + c + 1];
  float v2 = acc2 + bias[c + 2] + bias[RHF + c + 2] + bias[2 * RHF + c + 2];
  float v3 = acc3 + bias[c + 3] + bias[RHF + c + 3] + bias[2 * RHF + c + 3];
  v0 = v0 > 0.f ? v0 : (__expf(v0) - 1.f);
  v1 = v1 > 0.f ? v1 : (__expf(v1) - 1.f);
  v2 = v2 > 0.f ? v2 : (__expf(v2) - 1.f);
  v3 = v3 > 0.f ? v3 : (__expf(v3) - 1.f);
  float4 o = make_float4(v0, v1, v2, v3);
  *(float4*)(out + (size_t)n * RHF + c) = o;
}

extern "C" void kernel_launch(void* const* d_in, const int* in_sizes, int n_in,
                              void* d_out, int out_size, void* d_ws, size_t ws_size,
                              hipStream_t stream) {
  const float* x    = (const float*)d_in[0];
  const float* W    = (const float*)d_in[1];
  const float* al   = (const float*)d_in[2];
  const float* ar   = (const float*)d_in[3];
  const float* bias = (const float*)d_in[4];
  const int*   src  = (const int*)d_in[5];
  const int*   dst  = (const int*)d_in[6];
  float* out = (float*)d_out;

  // workspace layout (bytes), total ~223.2 MB
  char* p = (char*)d_ws;
  unsigned short* xb  = (unsigned short*)p; p += (size_t)RN * RIN * 2;        // 51.2 MB
  unsigned short* wbt = (unsigned short*)p; p += (size_t)RR * RIN * RHF * 2;  // 0.39 MB
  unsigned short* zb  = (unsigned short*)p; p += (size_t)RR * RN * RHF * 2;   // 153.6 MB
  float* el  = (float*)p; p += (size_t)N3 * RH * 4;                           // 4.8 MB
  float* er  = (float*)p; p += (size_t)N3 * RH * 4;                           // 4.8 MB
  int* deg   = (int*)p;   p += (size_t)N3 * 4;                                // 1.2 MB
  int* offs  = (int*)p;   p += (size_t)N3 * 4;                                // 1.2 MB
  int* eidx  = (int*)p;   p += (size_t)NE3 * 4;                               // 6.0 MB
  int* bsum  = (int*)p;   p += 2048;

  const int NB1 = (N3 + 1023) / 1024;   // 293 scan blocks

  hipMemsetAsync(deg, 0, (size_t)N3 * 4, stream);

  rgat_convx<<<(RN * RIN / 4 + 255) / 256, 256, 0, stream>>>(x, xb);
  rgat_convw<<<(RR * RIN * RHF + 255) / 256, 256, 0, stream>>>(W, wbt);

  rgat_gemm_bf16<<<dim3((RN + 127) / 128, RHF / 128, RR), 256, 0, stream>>>(xb, wbt, zb);
  rgat_logits<<<(RN + 3) / 4, 256, 0, stream>>>(zb, al, ar, el, er);

  rgat_hist<<<(NE3 + 255) / 256, 256, 0, stream>>>(dst, deg);
  rgat_scan1<<<NB1, 256, 0, stream>>>(deg, offs, bsum);
  rgat_scan2<<<1, 512, 0, stream>>>(bsum, NB1);
  rgat_scan3<<<NB1, 256, 0, stream>>>(offs, bsum);
  rgat_scatter<<<(NE3 + 255) / 256, 256, 0, stream>>>(dst, offs, eidx);

  rgat_aggregate<<<(RN + 3) / 4, 256, 0, stream>>>(zb, el, er, src, deg, offs,
                                                   eidx, bias, out);
}

// Round 3
// 752.979 us; speedup vs baseline: 2.9107x; 1.2389x over previous
//
#include <hip/hip_runtime.h>
#include <hip/hip_bf16.h>

// RGAT encoder, round 3:
//  - bf16 MFMA GEMM with fused attention-logit epilogue (el/er from f32 acc)
//  - CSR build; scatter also precomputes per-edge softmax numerators ee
//    (edge-parallel, latency-tolerant) into csr_ee/csr_src
//  - aggregate: block per node, wave w<3 owns relation w, SINGLE pass
//    (num += ee*z, den += ee), 1-deep z prefetch, LDS combine + bias + ELU.

#define RN 100000
#define RE 500000
#define RH 4
#define RIN 256
#define RR 3
#define RHF 256
#define NE3 (RR * RE)
#define N3  (RR * RN)

typedef __attribute__((ext_vector_type(8))) short short8;
typedef __attribute__((ext_vector_type(4))) float f32x4;

static __device__ __forceinline__ float b2f(unsigned short u) {
  return __uint_as_float(((unsigned int)u) << 16);
}
static __device__ __forceinline__ unsigned short f2b(float f) {
  unsigned int u = __float_as_uint(f);
  u += 0x7FFF + ((u >> 16) & 1);   // RNE
  return (unsigned short)(u >> 16);
}

// ---------------- conversions ----------------
__global__ __launch_bounds__(256) void rgat_convx(
    const float* __restrict__ x, unsigned short* __restrict__ xb) {
  const size_t i = ((size_t)blockIdx.x * 256 + threadIdx.x) * 4;
  if (i >= (size_t)RN * RIN) return;
  const float4 v = *(const float4*)(x + i);
  ushort4 o;
  o.x = f2b(v.x); o.y = f2b(v.y); o.z = f2b(v.z); o.w = f2b(v.w);
  *(ushort4*)(xb + i) = o;
}

// W[r][k][n] f32 -> Wbt[r][n][k] bf16
__global__ __launch_bounds__(256) void rgat_convw(
    const float* __restrict__ W, unsigned short* __restrict__ wbt) {
  const int o = blockIdx.x * 256 + threadIdx.x;
  if (o >= RR * RIN * RHF) return;
  const int r = o / (RIN * RHF);
  const int rem = o - r * (RIN * RHF);
  const int n = rem >> 8;
  const int k = rem & 255;
  wbt[o] = f2b(W[r * (RIN * RHF) + k * RHF + n]);
}

// ------- GEMM: zb[r] = xb @ Wbt[r]^T (bf16, f32 acc) + fused el/er ----------
__global__ __launch_bounds__(256) void rgat_gemm_bf16(
    const unsigned short* __restrict__ xb, const unsigned short* __restrict__ wbt,
    unsigned short* __restrict__ zb, const float* __restrict__ al,
    const float* __restrict__ ar, float* __restrict__ el,
    float* __restrict__ er) {
  __shared__ unsigned short As[128 * 32];
  __shared__ unsigned short Bs[128 * 32];
  const int tid = threadIdx.x;
  const int lane = tid & 63, wid = tid >> 6;
  const int wr = wid >> 1, wc = wid & 1;
  const int m0 = blockIdx.x * 128;
  const int n0 = blockIdx.y * 128;
  const int r  = blockIdx.z;

  f32x4 acc[4][4] = {};
  const unsigned short* Bbase = wbt + (size_t)r * (RIN * RHF);

  for (int k0 = 0; k0 < RIN; k0 += 32) {
#pragma unroll
    for (int i = 0; i < 2; ++i) {
      const int c = wid * 128 + i * 64 + lane;
      const int row = c >> 2, c4 = c & 3;
      const unsigned short* ga = xb + (size_t)(m0 + row) * RIN + k0 + c4 * 8;
      __builtin_amdgcn_global_load_lds(
          (const __attribute__((address_space(1))) void*)ga,
          (__attribute__((address_space(3))) void*)(As + (wid * 128 + i * 64) * 8),
          16, 0, 0);
      const unsigned short* gb = Bbase + (size_t)(n0 + row) * RIN + k0 + c4 * 8;
      __builtin_amdgcn_global_load_lds(
          (const __attribute__((address_space(1))) void*)gb,
          (__attribute__((address_space(3))) void*)(Bs + (wid * 128 + i * 64) * 8),
          16, 0, 0);
    }
    asm volatile("s_waitcnt vmcnt(0)" ::: "memory");
    __syncthreads();

    short8 af[4], bfr[4];
#pragma unroll
    for (int mi = 0; mi < 4; ++mi)
      af[mi] = *(const short8*)(As + ((wr * 64 + mi * 16 + (lane & 15)) * 32 + (lane >> 4) * 8));
#pragma unroll
    for (int ni = 0; ni < 4; ++ni)
      bfr[ni] = *(const short8*)(Bs + ((wc * 64 + ni * 16 + (lane & 15)) * 32 + (lane >> 4) * 8));
#pragma unroll
    for (int mi = 0; mi < 4; ++mi)
#pragma unroll
      for (int ni = 0; ni < 4; ++ni)
        acc[mi][ni] = __builtin_amdgcn_mfma_f32_16x16x32_bf16(af[mi], bfr[ni], acc[mi][ni], 0, 0, 0);
    __syncthreads();
  }

  // head owned by this (blockIdx.y, wc): cols head*64 .. head*64+63
  const int head = blockIdx.y * 2 + wc;
  float alv[4], arv[4];
#pragma unroll
  for (int ni = 0; ni < 4; ++ni) {
    alv[ni] = al[r * RHF + head * 64 + ni * 16 + (lane & 15)];
    arv[ni] = ar[r * RHF + head * 64 + ni * 16 + (lane & 15)];
  }

  const int mbase = m0 + wr * 64;
#pragma unroll
  for (int mi = 0; mi < 4; ++mi) {
#pragma unroll
    for (int q = 0; q < 4; ++q) {
      const int m = mbase + mi * 16 + (lane >> 4) * 4 + q;
      // attention logits: reduce over this head's 64 cols
      float pl = 0.f, pr = 0.f;
#pragma unroll
      for (int ni = 0; ni < 4; ++ni) {
        pl += acc[mi][ni][q] * alv[ni];
        pr += acc[mi][ni][q] * arv[ni];
      }
#pragma unroll
      for (int off = 1; off < 16; off <<= 1) {
        pl += __shfl_xor(pl, off);
        pr += __shfl_xor(pr, off);
      }
      if (m < RN) {
        if ((lane & 15) == 0) {
          el[(size_t)(r * (size_t)RN + m) * RH + head] = pl;
          er[(size_t)(r * (size_t)RN + m) * RH + head] = pr;
        }
        unsigned short* zrow = zb + (size_t)r * ((size_t)RN * RHF) + (size_t)m * RHF
                               + n0 + wc * 64 + (lane & 15);
#pragma unroll
        for (int ni = 0; ni < 4; ++ni) zrow[ni * 16] = f2b(acc[mi][ni][q]);
      }
    }
  }
}

// ---------------- CSR build ----------------
__global__ __launch_bounds__(256) void rgat_hist(
    const int* __restrict__ dst, int* __restrict__ deg) {
  const int i = blockIdx.x * 256 + threadIdx.x;
  if (i >= NE3) return;
  const int r = i / RE;
  atomicAdd(&deg[r * RN + dst[i]], 1);
}

__global__ __launch_bounds__(256) void rgat_scan1(
    const int* __restrict__ deg, int* __restrict__ offs, int* __restrict__ bsum) {
  __shared__ int sh[256];
  const int tid = threadIdx.x;
  const int base = blockIdx.x * 1024 + tid * 4;
  int v[4]; int s = 0;
#pragma unroll
  for (int j = 0; j < 4; ++j) {
    v[j] = (base + j < N3) ? deg[base + j] : 0;
    s += v[j];
  }
  sh[tid] = s;
  __syncthreads();
  for (int off = 1; off < 256; off <<= 1) {
    int t = (tid >= off) ? sh[tid - off] : 0;
    __syncthreads();
    sh[tid] += t;
    __syncthreads();
  }
  int run = sh[tid] - s;
  if (tid == 255) bsum[blockIdx.x] = sh[255];
#pragma unroll
  for (int j = 0; j < 4; ++j) {
    if (base + j < N3) offs[base + j] = run;
    run += v[j];
  }
}

__global__ __launch_bounds__(512) void rgat_scan2(int* __restrict__ bsum, int nb) {
  __shared__ int sh[512];
  const int tid = threadIdx.x;
  const int v = (tid < nb) ? bsum[tid] : 0;
  sh[tid] = v;
  __syncthreads();
  for (int off = 1; off < 512; off <<= 1) {
    int t = (tid >= off) ? sh[tid - off] : 0;
    __syncthreads();
    sh[tid] += t;
    __syncthreads();
  }
  if (tid < nb) bsum[tid] = sh[tid] - v;
}

__global__ __launch_bounds__(256) void rgat_scan3(
    int* __restrict__ offs, const int* __restrict__ bsum) {
  const int base = blockIdx.x * 1024 + threadIdx.x * 4;
  const int b = bsum[blockIdx.x];
#pragma unroll
  for (int j = 0; j < 4; ++j)
    if (base + j < N3) offs[base + j] += b;
}

// scatter + edge softmax numerator: csr_src[pos]=src, csr_ee[pos]=exp(lrelu(el+er))
__global__ __launch_bounds__(256) void rgat_scatter(
    const int* __restrict__ src, const int* __restrict__ dst,
    const float* __restrict__ el, const float* __restrict__ er,
    int* __restrict__ offs, int* __restrict__ csr_src,
    float4* __restrict__ csr_ee) {
  const int i = blockIdx.x * 256 + threadIdx.x;
  if (i >= NE3) return;
  const int r = i / RE;
  const int s = src[i];
  const int d = dst[i];
  const int pos = atomicAdd(&offs[r * RN + d], 1);
  const float4 elv = *(const float4*)(el + (size_t)(r * (size_t)RN + s) * RH);
  const float4 erv = *(const float4*)(er + (size_t)(r * (size_t)RN + d) * RH);
  float e0 = elv.x + erv.x, e1 = elv.y + erv.y, e2 = elv.z + erv.z, e3 = elv.w + erv.w;
  e0 = e0 > 0.f ? e0 : 0.2f * e0;
  e1 = e1 > 0.f ? e1 : 0.2f * e1;
  e2 = e2 > 0.f ? e2 : 0.2f * e2;
  e3 = e3 > 0.f ? e3 : 0.2f * e3;
  csr_src[pos] = s;
  csr_ee[pos] = make_float4(__expf(e0), __expf(e1), __expf(e2), __expf(e3));
}

// -------- aggregate: block per node; wave w<3 owns relation w; single pass ---
__global__ __launch_bounds__(256) void rgat_aggregate(
    const unsigned short* __restrict__ zb, const int* __restrict__ csr_src,
    const float4* __restrict__ csr_ee, const int* __restrict__ deg,
    const int* __restrict__ offs, const float* __restrict__ bias,
    float* __restrict__ out) {
  __shared__ float sh[3][RHF];
  const int n = blockIdx.x;
  const int wid = threadIdx.x >> 6, lane = threadIdx.x & 63;
  const int h = lane >> 4;
  const int c = lane * 4;

  if (wid < 3) {
    const int r = wid;
    const int base = r * RN + n;
    const int d = deg[base];
    float a0 = 0.f, a1 = 0.f, a2 = 0.f, a3 = 0.f, den = 0.f;
    if (d > 0) {
      const int start = offs[base] - d;   // offs is segment END after scatter
      const unsigned short* zr = zb + (size_t)r * ((size_t)RN * RHF) + c;
      int s = csr_src[start];
      float4 ee = csr_ee[start];
      ushort4 zv = *(const ushort4*)(zr + (size_t)s * RHF);
      for (int e = 0; e < d; ++e) {
        const float a = (h == 0) ? ee.x : (h == 1) ? ee.y : (h == 2) ? ee.z : ee.w;
        const ushort4 zc = zv;
        if (e + 1 < d) {
          s = csr_src[start + e + 1];
          ee = csr_ee[start + e + 1];
          zv = *(const ushort4*)(zr + (size_t)s * RHF);
        }
        a0 += a * b2f(zc.x);
        a1 += a * b2f(zc.y);
        a2 += a * b2f(zc.z);
        a3 += a * b2f(zc.w);
        den += a;
      }
    }
    const float inv = (den > 0.f) ? 1.f / den : 0.f;
    *(float4*)&sh[r][c] = make_float4(a0 * inv, a1 * inv, a2 * inv, a3 * inv);
  }
  __syncthreads();

  const int col = threadIdx.x;
  float v = sh[0][col] + sh[1][col] + sh[2][col]
          + bias[col] + bias[RHF + col] + bias[2 * RHF + col];
  v = v > 0.f ? v : (__expf(v) - 1.f);
  out[(size_t)n * RHF + col] = v;
}

extern "C" void kernel_launch(void* const* d_in, const int* in_sizes, int n_in,
                              void* d_out, int out_size, void* d_ws, size_t ws_size,
                              hipStream_t stream) {
  const float* x    = (const float*)d_in[0];
  const float* W    = (const float*)d_in[1];
  const float* al   = (const float*)d_in[2];
  const float* ar   = (const float*)d_in[3];
  const float* bias = (const float*)d_in[4];
  const int*   src  = (const int*)d_in[5];
  const int*   dst  = (const int*)d_in[6];
  float* out = (float*)d_out;

  // workspace layout (bytes), total ~247 MB
  char* p = (char*)d_ws;
  unsigned short* xb  = (unsigned short*)p; p += (size_t)RN * RIN * 2;        // 51.2 MB
  unsigned short* wbt = (unsigned short*)p; p += (size_t)RR * RIN * RHF * 2;  // 0.39 MB
  unsigned short* zb  = (unsigned short*)p; p += (size_t)RR * RN * RHF * 2;   // 153.6 MB
  float* el   = (float*)p;  p += (size_t)N3 * RH * 4;                         // 4.8 MB
  float* er   = (float*)p;  p += (size_t)N3 * RH * 4;                         // 4.8 MB
  int* deg    = (int*)p;    p += (size_t)N3 * 4;                              // 1.2 MB
  int* offs   = (int*)p;    p += (size_t)N3 * 4;                              // 1.2 MB
  int* csr_s  = (int*)p;    p += (size_t)NE3 * 4;                             // 6.0 MB
  float4* csr_ee = (float4*)p; p += (size_t)NE3 * 16;                         // 24.0 MB
  int* bsum   = (int*)p;    p += 2048;

  const int NB1 = (N3 + 1023) / 1024;

  hipMemsetAsync(deg, 0, (size_t)N3 * 4, stream);

  rgat_convx<<<(RN * RIN / 4 + 255) / 256, 256, 0, stream>>>(x, xb);
  rgat_convw<<<(RR * RIN * RHF + 255) / 256, 256, 0, stream>>>(W, wbt);

  rgat_hist<<<(NE3 + 255) / 256, 256, 0, stream>>>(dst, deg);
  rgat_scan1<<<NB1, 256, 0, stream>>>(deg, offs, bsum);
  rgat_scan2<<<1, 512, 0, stream>>>(bsum, NB1);
  rgat_scan3<<<NB1, 256, 0, stream>>>(offs, bsum);

  rgat_gemm_bf16<<<dim3((RN + 127) / 128, RHF / 128, RR), 256, 0, stream>>>(
      xb, wbt, zb, al, ar, el, er);

  rgat_scatter<<<(NE3 + 255) / 256, 256, 0, stream>>>(src, dst, el, er, offs,
                                                      csr_s, csr_ee);

  rgat_aggregate<<<RN, 256, 0, stream>>>(zb, csr_s, csr_ee, deg, offs, bias, out);
}

// Round 4
// 646.519 us; speedup vs baseline: 3.3900x; 1.1647x over previous
//
#include <hip/hip_runtime.h>
#include <hip/hip_bf16.h>

// RGAT encoder, round 4:
//  - bf16 MFMA GEMM with fused attention-logit epilogue (unchanged)
//  - MERGED CSR across relations: one segment per node, entry zoff = r*RN+src
//  - aggregate: block per node, ALL 4 waves split the merged segment,
//    4-wide batched loads (4 independent csr->z chains in flight),
//    per-relation (num,den) register accumulators, LDS combine + bias + ELU.

#define RN 100000
#define RE 500000
#define RH 4
#define RIN 256
#define RR 3
#define RHF 256
#define NE3 (RR * RE)

typedef __attribute__((ext_vector_type(8))) short short8;
typedef __attribute__((ext_vector_type(4))) float f32x4;

static __device__ __forceinline__ float b2f(unsigned short u) {
  return __uint_as_float(((unsigned int)u) << 16);
}
static __device__ __forceinline__ unsigned short f2b(float f) {
  unsigned int u = __float_as_uint(f);
  u += 0x7FFF + ((u >> 16) & 1);   // RNE
  return (unsigned short)(u >> 16);
}

// ---------------- conversions ----------------
__global__ __launch_bounds__(256) void rgat_convx(
    const float* __restrict__ x, unsigned short* __restrict__ xb) {
  const size_t i = ((size_t)blockIdx.x * 256 + threadIdx.x) * 4;
  if (i >= (size_t)RN * RIN) return;
  const float4 v = *(const float4*)(x + i);
  ushort4 o;
  o.x = f2b(v.x); o.y = f2b(v.y); o.z = f2b(v.z); o.w = f2b(v.w);
  *(ushort4*)(xb + i) = o;
}

// W[r][k][n] f32 -> Wbt[r][n][k] bf16
__global__ __launch_bounds__(256) void rgat_convw(
    const float* __restrict__ W, unsigned short* __restrict__ wbt) {
  const int o = blockIdx.x * 256 + threadIdx.x;
  if (o >= RR * RIN * RHF) return;
  const int r = o / (RIN * RHF);
  const int rem = o - r * (RIN * RHF);
  const int n = rem >> 8;
  const int k = rem & 255;
  wbt[o] = f2b(W[r * (RIN * RHF) + k * RHF + n]);
}

// ------- GEMM: zb[r] = xb @ Wbt[r]^T (bf16, f32 acc) + fused el/er ----------
__global__ __launch_bounds__(256) void rgat_gemm_bf16(
    const unsigned short* __restrict__ xb, const unsigned short* __restrict__ wbt,
    unsigned short* __restrict__ zb, const float* __restrict__ al,
    const float* __restrict__ ar, float* __restrict__ el,
    float* __restrict__ er) {
  __shared__ unsigned short As[128 * 32];
  __shared__ unsigned short Bs[128 * 32];
  const int tid = threadIdx.x;
  const int lane = tid & 63, wid = tid >> 6;
  const int wr = wid >> 1, wc = wid & 1;
  const int m0 = blockIdx.x * 128;
  const int n0 = blockIdx.y * 128;
  const int r  = blockIdx.z;

  f32x4 acc[4][4] = {};
  const unsigned short* Bbase = wbt + (size_t)r * (RIN * RHF);

  for (int k0 = 0; k0 < RIN; k0 += 32) {
#pragma unroll
    for (int i = 0; i < 2; ++i) {
      const int c = wid * 128 + i * 64 + lane;
      const int row = c >> 2, c4 = c & 3;
      const unsigned short* ga = xb + (size_t)(m0 + row) * RIN + k0 + c4 * 8;
      __builtin_amdgcn_global_load_lds(
          (const __attribute__((address_space(1))) void*)ga,
          (__attribute__((address_space(3))) void*)(As + (wid * 128 + i * 64) * 8),
          16, 0, 0);
      const unsigned short* gb = Bbase + (size_t)(n0 + row) * RIN + k0 + c4 * 8;
      __builtin_amdgcn_global_load_lds(
          (const __attribute__((address_space(1))) void*)gb,
          (__attribute__((address_space(3))) void*)(Bs + (wid * 128 + i * 64) * 8),
          16, 0, 0);
    }
    asm volatile("s_waitcnt vmcnt(0)" ::: "memory");
    __syncthreads();

    short8 af[4], bfr[4];
#pragma unroll
    for (int mi = 0; mi < 4; ++mi)
      af[mi] = *(const short8*)(As + ((wr * 64 + mi * 16 + (lane & 15)) * 32 + (lane >> 4) * 8));
#pragma unroll
    for (int ni = 0; ni < 4; ++ni)
      bfr[ni] = *(const short8*)(Bs + ((wc * 64 + ni * 16 + (lane & 15)) * 32 + (lane >> 4) * 8));
#pragma unroll
    for (int mi = 0; mi < 4; ++mi)
#pragma unroll
      for (int ni = 0; ni < 4; ++ni)
        acc[mi][ni] = __builtin_amdgcn_mfma_f32_16x16x32_bf16(af[mi], bfr[ni], acc[mi][ni], 0, 0, 0);
    __syncthreads();
  }

  const int head = blockIdx.y * 2 + wc;
  float alv[4], arv[4];
#pragma unroll
  for (int ni = 0; ni < 4; ++ni) {
    alv[ni] = al[r * RHF + head * 64 + ni * 16 + (lane & 15)];
    arv[ni] = ar[r * RHF + head * 64 + ni * 16 + (lane & 15)];
  }

  const int mbase = m0 + wr * 64;
#pragma unroll
  for (int mi = 0; mi < 4; ++mi) {
#pragma unroll
    for (int q = 0; q < 4; ++q) {
      const int m = mbase + mi * 16 + (lane >> 4) * 4 + q;
      float pl = 0.f, pr = 0.f;
#pragma unroll
      for (int ni = 0; ni < 4; ++ni) {
        pl += acc[mi][ni][q] * alv[ni];
        pr += acc[mi][ni][q] * arv[ni];
      }
#pragma unroll
      for (int off = 1; off < 16; off <<= 1) {
        pl += __shfl_xor(pl, off);
        pr += __shfl_xor(pr, off);
      }
      if (m < RN) {
        if ((lane & 15) == 0) {
          el[(size_t)(r * (size_t)RN + m) * RH + head] = pl;
          er[(size_t)(r * (size_t)RN + m) * RH + head] = pr;
        }
        unsigned short* zrow = zb + (size_t)r * ((size_t)RN * RHF) + (size_t)m * RHF
                               + n0 + wc * 64 + (lane & 15);
#pragma unroll
        for (int ni = 0; ni < 4; ++ni) zrow[ni * 16] = f2b(acc[mi][ni][q]);
      }
    }
  }
}

// ---------------- merged CSR build (segments over nodes, all relations) -----
__global__ __launch_bounds__(256) void rgat_hist(
    const int* __restrict__ dst, int* __restrict__ degm) {
  const int i = blockIdx.x * 256 + threadIdx.x;
  if (i >= NE3) return;
  atomicAdd(&degm[dst[i]], 1);
}

__global__ __launch_bounds__(256) void rgat_scan1(
    const int* __restrict__ deg, int* __restrict__ offs, int* __restrict__ bsum) {
  __shared__ int sh[256];
  const int tid = threadIdx.x;
  const int base = blockIdx.x * 1024 + tid * 4;
  int v[4]; int s = 0;
#pragma unroll
  for (int j = 0; j < 4; ++j) {
    v[j] = (base + j < RN) ? deg[base + j] : 0;
    s += v[j];
  }
  sh[tid] = s;
  __syncthreads();
  for (int off = 1; off < 256; off <<= 1) {
    int t = (tid >= off) ? sh[tid - off] : 0;
    __syncthreads();
    sh[tid] += t;
    __syncthreads();
  }
  int run = sh[tid] - s;
  if (tid == 255) bsum[blockIdx.x] = sh[255];
#pragma unroll
  for (int j = 0; j < 4; ++j) {
    if (base + j < RN) offs[base + j] = run;
    run += v[j];
  }
}

__global__ __launch_bounds__(512) void rgat_scan2(int* __restrict__ bsum, int nb) {
  __shared__ int sh[512];
  const int tid = threadIdx.x;
  const int v = (tid < nb) ? bsum[tid] : 0;
  sh[tid] = v;
  __syncthreads();
  for (int off = 1; off < 512; off <<= 1) {
    int t = (tid >= off) ? sh[tid - off] : 0;
    __syncthreads();
    sh[tid] += t;
    __syncthreads();
  }
  if (tid < nb) bsum[tid] = sh[tid] - v;
}

__global__ __launch_bounds__(256) void rgat_scan3(
    int* __restrict__ offs, const int* __restrict__ bsum) {
  const int base = blockIdx.x * 1024 + threadIdx.x * 4;
  const int b = bsum[blockIdx.x];
#pragma unroll
  for (int j = 0; j < 4; ++j)
    if (base + j < RN) offs[base + j] += b;
}

// scatter: czoff[pos] = r*RN+src (relation recoverable), cee[pos] = exp numerators
__global__ __launch_bounds__(256) void rgat_scatter(
    const int* __restrict__ src, const int* __restrict__ dst,
    const float* __restrict__ el, const float* __restrict__ er,
    int* __restrict__ offsm, int* __restrict__ czoff,
    float4* __restrict__ cee) {
  const int i = blockIdx.x * 256 + threadIdx.x;
  if (i >= NE3) return;
  const int r = i / RE;
  const int s = src[i];
  const int d = dst[i];
  const int pos = atomicAdd(&offsm[d], 1);
  const float4 elv = *(const float4*)(el + (size_t)(r * (size_t)RN + s) * RH);
  const float4 erv = *(const float4*)(er + (size_t)(r * (size_t)RN + d) * RH);
  float e0 = elv.x + erv.x, e1 = elv.y + erv.y, e2 = elv.z + erv.z, e3 = elv.w + erv.w;
  e0 = e0 > 0.f ? e0 : 0.2f * e0;
  e1 = e1 > 0.f ? e1 : 0.2f * e1;
  e2 = e2 > 0.f ? e2 : 0.2f * e2;
  e3 = e3 > 0.f ? e3 : 0.2f * e3;
  czoff[pos] = r * RN + s;
  cee[pos] = make_float4(__expf(e0), __expf(e1), __expf(e2), __expf(e3));
}

// -------- aggregate: block per node; 4 waves split merged segment ------------
__global__ __launch_bounds__(256) void rgat_aggregate(
    const unsigned short* __restrict__ zb, const int* __restrict__ czoff,
    const float4* __restrict__ cee, const int* __restrict__ degm,
    const int* __restrict__ offsm, const float* __restrict__ bias,
    float* __restrict__ out) {
  __shared__ float shn[4][RR][RHF];   // 12 KB
  __shared__ float shd[4][RR][RH];
  const int n = blockIdx.x;
  const int wid = threadIdx.x >> 6, lane = threadIdx.x & 63;
  const int h = lane >> 4;
  const int c = lane * 4;

  const int d = degm[n];
  const int start = offsm[n] - d;   // offsm is segment END after scatter

  float4 acc0 = {0.f, 0.f, 0.f, 0.f}, acc1 = acc0, acc2 = acc0;
  float den0 = 0.f, den1 = 0.f, den2 = 0.f;

  const unsigned short* zc = zb + c;

  for (int base = wid; base < d; base += 16) {
    int zo[4];
    float4 ef[4];
    ushort4 zv[4];
#pragma unroll
    for (int j = 0; j < 4; ++j) {
      const int t = base + j * 4;
      if (t < d) {
        zo[j] = czoff[start + t];
        ef[j] = cee[start + t];
      } else {
        zo[j] = -1;
      }
    }
#pragma unroll
    for (int j = 0; j < 4; ++j)
      if (zo[j] >= 0) zv[j] = *(const ushort4*)(zc + (size_t)zo[j] * RHF);
#pragma unroll
    for (int j = 0; j < 4; ++j) {
      if (zo[j] < 0) continue;
      const float a = (h == 0) ? ef[j].x : (h == 1) ? ef[j].y : (h == 2) ? ef[j].z : ef[j].w;
      const float z0 = b2f(zv[j].x), z1 = b2f(zv[j].y), z2 = b2f(zv[j].z), z3 = b2f(zv[j].w);
      if (zo[j] < RN) {
        acc0.x += a * z0; acc0.y += a * z1; acc0.z += a * z2; acc0.w += a * z3; den0 += a;
      } else if (zo[j] < 2 * RN) {
        acc1.x += a * z0; acc1.y += a * z1; acc1.z += a * z2; acc1.w += a * z3; den1 += a;
      } else {
        acc2.x += a * z0; acc2.y += a * z1; acc2.z += a * z2; acc2.w += a * z3; den2 += a;
      }
    }
  }

  *(float4*)&shn[wid][0][c] = acc0;
  *(float4*)&shn[wid][1][c] = acc1;
  *(float4*)&shn[wid][2][c] = acc2;
  if ((lane & 15) == 0) {
    shd[wid][0][h] = den0;
    shd[wid][1][h] = den1;
    shd[wid][2][h] = den2;
  }
  __syncthreads();

  const int col = threadIdx.x;
  const int hh = col >> 6;
  float v = bias[col] + bias[RHF + col] + bias[2 * RHF + col];
#pragma unroll
  for (int r = 0; r < RR; ++r) {
    const float dn = shd[0][r][hh] + shd[1][r][hh] + shd[2][r][hh] + shd[3][r][hh];
    const float nm = shn[0][r][col] + shn[1][r][col] + shn[2][r][col] + shn[3][r][col];
    v += (dn > 0.f) ? nm / dn : 0.f;
  }
  v = v > 0.f ? v : (__expf(v) - 1.f);
  out[(size_t)n * RHF + col] = v;
}

extern "C" void kernel_launch(void* const* d_in, const int* in_sizes, int n_in,
                              void* d_out, int out_size, void* d_ws, size_t ws_size,
                              hipStream_t stream) {
  const float* x    = (const float*)d_in[0];
  const float* W    = (const float*)d_in[1];
  const float* al   = (const float*)d_in[2];
  const float* ar   = (const float*)d_in[3];
  const float* bias = (const float*)d_in[4];
  const int*   src  = (const int*)d_in[5];
  const int*   dst  = (const int*)d_in[6];
  float* out = (float*)d_out;

  // workspace layout (bytes), total ~246 MB
  char* p = (char*)d_ws;
  unsigned short* xb  = (unsigned short*)p; p += (size_t)RN * RIN * 2;        // 51.2 MB
  unsigned short* wbt = (unsigned short*)p; p += (size_t)RR * RIN * RHF * 2;  // 0.39 MB
  unsigned short* zb  = (unsigned short*)p; p += (size_t)RR * RN * RHF * 2;   // 153.6 MB
  float* el    = (float*)p;  p += (size_t)RR * RN * RH * 4;                   // 4.8 MB
  float* er    = (float*)p;  p += (size_t)RR * RN * RH * 4;                   // 4.8 MB
  int* degm    = (int*)p;    p += (size_t)RN * 4;                             // 0.4 MB
  int* offsm   = (int*)p;    p += (size_t)RN * 4;                             // 0.4 MB
  int* czoff   = (int*)p;    p += (size_t)NE3 * 4;                            // 6.0 MB
  float4* cee  = (float4*)p; p += (size_t)NE3 * 16;                           // 24.0 MB
  int* bsum    = (int*)p;    p += 2048;

  const int NB1 = (RN + 1023) / 1024;   // 98

  hipMemsetAsync(degm, 0, (size_t)RN * 4, stream);

  rgat_convx<<<(RN * RIN / 4 + 255) / 256, 256, 0, stream>>>(x, xb);
  rgat_convw<<<(RR * RIN * RHF + 255) / 256, 256, 0, stream>>>(W, wbt);

  rgat_hist<<<(NE3 + 255) / 256, 256, 0, stream>>>(dst, degm);
  rgat_scan1<<<NB1, 256, 0, stream>>>(degm, offsm, bsum);
  rgat_scan2<<<1, 512, 0, stream>>>(bsum, NB1);
  rgat_scan3<<<NB1, 256, 0, stream>>>(offsm, bsum);

  rgat_gemm_bf16<<<dim3((RN + 127) / 128, RHF / 128, RR), 256, 0, stream>>>(
      xb, wbt, zb, al, ar, el, er);

  rgat_scatter<<<(NE3 + 255) / 256, 256, 0, stream>>>(src, dst, el, er, offsm,
                                                      czoff, cee);

  rgat_aggregate<<<RN, 256, 0, stream>>>(zb, czoff, cee, degm, offsm, bias, out);
}